// Round 13
// baseline (122.939 us; speedup 1.0000x reference)
//
#include <hip/hip_runtime.h>
#include <hip/hip_bf16.h>

// Fused Swin window attention for MI355X (gfx950) — round 13: r9 + RT dbuf.
// History: r9=116.5us (head-partition, 3 blocks/CU). r10 (4 blocks/CU) spilled
// via VGPR cap; r11 (dual-acc ILP) spilled via AGPR headroom; r12 (phase3/4
// pipelining) was slightly NEGATIVE (121us) — compiler scheduling is already
// near-optimal in this structure. This round makes ONE change to r9:
//   Phase 2's 12 LDS round-trips shared ONE per-wave buffer -> in-order DS +
//   buffer-reuse WAR exposed ~200cyc of DS latency per round-trip. Now TWO
//   16x72 buffers: chunk i writes bufA/bufB, chunk i+1's 64-MFMA GEMM issues,
//   THEN chunk i's fragments are read back — write->read separated by ~310cyc
//   of MFMA, DS latency fully hidden. Phase 3's P round-trip alternates
//   buffers too. LDS 44,032 -> 52,224 B (still 3 blocks/CU: 156.7KB < 160KB).
// Phases 1/3/4 + epilogue are r9 VERBATIM.

typedef __attribute__((ext_vector_type(8))) short bf16x8;
typedef __attribute__((ext_vector_type(4))) float f32x4;

__device__ __forceinline__ f32x4 mfma16(bf16x8 a, bf16x8 b, f32x4 c) {
  return __builtin_amdgcn_mfma_f32_16x16x32_bf16(a, b, c, 0, 0, 0);
}

__device__ __forceinline__ unsigned short f2bf(float f) {
  __hip_bfloat16 h = __float2bfloat16(f);
  return *reinterpret_cast<unsigned short*>(&h);
}

__device__ __forceinline__ uint2 pack4(float a, float b, float c, float d) {
  union { unsigned short u[4]; uint2 v; } pk;
  pk.u[0] = f2bf(a); pk.u[1] = f2bf(b); pk.u[2] = f2bf(c); pk.u[3] = f2bf(d);
  return pk.v;
}

#define LOG2E 1.4426950408889634f
#define EXPSCALE (0.17677669529663687f * 1.4426950408889634f)

// LDS layout (ushort elements); row strides multiples of 8 elem (16B) for b128.
#define XO  264           // x / oh region row stride (64 rows)
#define SB  72            // scratch buffer row stride (16 rows)
#define SBUF 1152         // one scratch buffer: 16*72
#define RT_PER_WAVE 2304  // two buffers per wave
#define OFF_RT 16896      // 64*264
#define SMEM_ELTS 26112   // 16896 + 4*2304 = 52,224 B -> 3 blocks/CU

// Weight tiled layout: elem(n,k) -> ((((n>>4)*8+(k>>5))*4+((k>>3)&3))*16+(n&15))*8+(k&7)
__global__ void prep_kernel(const float* __restrict__ w_qkv,
                            const float* __restrict__ w_out,
                            const float* __restrict__ pos_emb,
                            unsigned short* __restrict__ wqkvT,
                            unsigned short* __restrict__ woutT,
                            float* __restrict__ bias64) {
  const int stride = gridDim.x * blockDim.x;
  const int tid = blockIdx.x * blockDim.x + threadIdx.x;
  for (int i = tid; i < 768 * 256; i += stride) {
    int n = i >> 8, k = i & 255;
    int off = ((((n >> 4) * 8 + (k >> 5)) * 4 + ((k >> 3) & 3)) * 16 + (n & 15)) * 8 + (k & 7);
    wqkvT[off] = f2bf(w_qkv[k * 768 + n]);
  }
  for (int i = tid; i < 256 * 256; i += stride) {
    int n = i >> 8, k = i & 255;
    int off = ((((n >> 4) * 8 + (k >> 5)) * 4 + ((k >> 3) & 3)) * 16 + (n & 15)) * 8 + (k & 7);
    woutT[off] = f2bf(w_out[k * 256 + n]);
  }
  for (int i = tid; i < 64 * 64; i += stride) {
    int a = i >> 6, b = i & 63;
    int d0 = (b >> 3) - (a >> 3) + 7;
    int d1 = (b & 7) - (a & 7) + 7;
    bias64[i] = pos_emb[d0 * 15 + d1] * LOG2E;   // pre-scaled for exp2
  }
}

// 64px x 32col GEMM slice. SWAP=true: acc = mfma(w, x) -> (feat row, px col).
// SWAP=false: acc = mfma(x, w) -> (px row, feat col).
template <bool SWAP>
__device__ __forceinline__ void gemm32(f32x4 (&acc)[4][2],
                                       const unsigned short* __restrict__ a_lds,
                                       const unsigned short* __restrict__ wT,
                                       int col0, int l15, int lq) {
  const f32x4 zero4 = {0.f, 0.f, 0.f, 0.f};
#pragma unroll
  for (int rt = 0; rt < 4; ++rt)
#pragma unroll
    for (int ct = 0; ct < 2; ++ct) acc[rt][ct] = zero4;
#pragma unroll
  for (int kk = 0; kk < 8; ++kk) {
    bf16x8 a[4], b[2];
#pragma unroll
    for (int rt = 0; rt < 4; ++rt)
      a[rt] = *(const bf16x8*)&a_lds[(rt * 16 + l15) * XO + kk * 32 + lq * 8];
#pragma unroll
    for (int ct = 0; ct < 2; ++ct)
      b[ct] = *(const bf16x8*)&wT[((((col0 >> 4) + ct) * 8 + kk) * 4 + lq) * 128 + l15 * 8];
#pragma unroll
    for (int rt = 0; rt < 4; ++rt)
#pragma unroll
      for (int ct = 0; ct < 2; ++ct)
        acc[rt][ct] = SWAP ? mfma16(b[ct], a[rt], acc[rt][ct])
                           : mfma16(a[rt], b[ct], acc[rt][ct]);
  }
}

__global__ __launch_bounds__(256, 3)
void winattn_kernel(const float* __restrict__ x,
                    const unsigned short* __restrict__ wqkvT,
                    const unsigned short* __restrict__ woutT,
                    const float* __restrict__ bias64,
                    const float* __restrict__ b_out,
                    float* __restrict__ out) {
  __shared__ unsigned short smem[SMEM_ELTS];

  const int tid = threadIdx.x;
  const int lane = tid & 63;
  const int w = tid >> 6;
  const int l15 = lane & 15;
  const int lq = lane >> 4;

  const int bid = blockIdx.x;
  const int win = bid & 255;
  const int img = bid >> 8;
  const int wy = win >> 4, wx = win & 15;

  unsigned short* x_lds  = smem;                 // phase 1-2: x; phase 3-4: oh
  unsigned short* oh_lds = smem;
  unsigned short* bufA = smem + OFF_RT + w * RT_PER_WAVE;   // wave-private
  unsigned short* bufB = bufA + SBUF;

  const f32x4 zero4 = {0.f, 0.f, 0.f, 0.f};
  const size_t img_base = (size_t)img * 128 * 128 * 256;

  // ---------- phase 1: stage x window -> bf16 LDS (coalesced) ----------
  {
#pragma unroll
    for (int r = 0; r < 16; ++r) {
      int p = r * 4 + w;                 // pixel 0..63
      const float* src = x + img_base +
          (((size_t)(wy * 8 + (p >> 3)) * 128) + (wx * 8 + (p & 7))) * 256 + lane * 4;
      float4 v4 = *(const float4*)src;
      *(uint2*)&x_lds[p * XO + lane * 4] = pack4(v4.x, v4.y, v4.z, v4.w);
    }
  }
  __syncthreads();   // bar1

  // ---------- phase 2: q/k/v, round-trips double-buffered + deferred ----------
  // Write (C-frag) of chunk i -> bufA(h2=0)/bufB(h2=1); then chunk i+1's GEMM
  // (64 MFMA) issues; THEN chunk i's fragments are read back. The write->read
  // gap is filled with matrix work, hiding the in-order DS latency.
  // qf/kf[rt][hh]: A/B-frag, (px rt*16+l15, feat hh*32+lq*8..+8)
  // vf[ft][h2][hh]: A-frag of vT, (feat hh*32+ft*16+l15, kv px h2*32+lq*8..+8)
  bf16x8 qf[4][2], kf[4][2], vf[2][2][2];

  // q/k tile write: rows = px low (l15), col = rr*32 (px hi) + ct*16+lq*4 (feat)
#define WQK(BUF, H2)                                                        \
  _Pragma("unroll")                                                         \
  for (int rr = 0; rr < 2; ++rr)                                            \
    _Pragma("unroll")                                                       \
    for (int ct = 0; ct < 2; ++ct)                                          \
      *(uint2*)&BUF[l15 * SB + rr * 32 + ct * 16 + lq * 4] =                \
          pack4(acc[(H2) * 2 + rr][ct][0], acc[(H2) * 2 + rr][ct][1],       \
                acc[(H2) * 2 + rr][ct][2], acc[(H2) * 2 + rr][ct][3]);
#define RQK(BUF, H2, DEST, HH)                                              \
  _Pragma("unroll")                                                         \
  for (int rr = 0; rr < 2; ++rr)                                            \
    DEST[(H2) * 2 + rr][HH] =                                               \
        *(const bf16x8*)&BUF[l15 * SB + rr * 32 + lq * 8];

  // v tile write (transpose): rows = feat low (l15), col = ct*32 (feat hi) +
  // rr*16+lq*4 (px within h2 group)
#define WV(BUF, H2)                                                         \
  _Pragma("unroll")                                                         \
  for (int rr = 0; rr < 2; ++rr)                                            \
    _Pragma("unroll")                                                       \
    for (int ct = 0; ct < 2; ++ct)                                          \
      *(uint2*)&BUF[l15 * SB + ct * 32 + rr * 16 + lq * 4] =                \
          pack4(acc[(H2) * 2 + rr][ct][0], acc[(H2) * 2 + rr][ct][1],       \
                acc[(H2) * 2 + rr][ct][2], acc[(H2) * 2 + rr][ct][3]);
#define RV(BUF, H2, HH)                                                     \
  _Pragma("unroll")                                                         \
  for (int ft = 0; ft < 2; ++ft)                                            \
    vf[ft][(H2)][HH] =                                                      \
        *(const bf16x8*)&BUF[l15 * SB + ft * 32 + lq * 8];

  {
    f32x4 acc[4][2];
    gemm32<true >(acc, x_lds, wqkvT,       w * 64 +  0, l15, lq);  // G0: q hh0
    WQK(bufA, 0) WQK(bufB, 1)
    gemm32<true >(acc, x_lds, wqkvT,       w * 64 + 32, l15, lq);  // G1: q hh1
    RQK(bufA, 0, qf, 0) RQK(bufB, 1, qf, 0)
    WQK(bufA, 0) WQK(bufB, 1)
    gemm32<true >(acc, x_lds, wqkvT, 256 + w * 64 +  0, l15, lq);  // G2: k hh0
    RQK(bufA, 0, qf, 1) RQK(bufB, 1, qf, 1)
    WQK(bufA, 0) WQK(bufB, 1)
    gemm32<true >(acc, x_lds, wqkvT, 256 + w * 64 + 32, l15, lq);  // G3: k hh1
    RQK(bufA, 0, kf, 0) RQK(bufB, 1, kf, 0)
    WQK(bufA, 0) WQK(bufB, 1)
    gemm32<false>(acc, x_lds, wqkvT, 512 + w * 64 +  0, l15, lq);  // G4: v hh0
    RQK(bufA, 0, kf, 1) RQK(bufB, 1, kf, 1)
    WV(bufA, 0) WV(bufB, 1)
    gemm32<false>(acc, x_lds, wqkvT, 512 + w * 64 + 32, l15, lq);  // G5: v hh1
    RV(bufA, 0, 0) RV(bufB, 1, 0)
    WV(bufA, 0) WV(bufB, 1)
    RV(bufA, 0, 1) RV(bufB, 1, 1)
  }
  __syncthreads();   // bar2: all x reads done -> oh region (overlays x) safe

  // ---------- phase 3: attention for heads {2w, 2w+1} (r9, P buf alternates) ----------
#pragma unroll
  for (int it = 0; it < 4; ++it) {
    f32x4 bias4[4];
#pragma unroll
    for (int jt = 0; jt < 4; ++jt)
      bias4[jt] = *(const f32x4*)&bias64[(it * 16 + l15) * 64 + jt * 16 + lq * 4];
#pragma unroll
    for (int hh = 0; hh < 2; ++hh) {
      unsigned short* pb = (hh & 1) ? bufB : bufA;
      // S^T = mfma(k, q): D[kv jt*16+lq*4+r][q px it*16+l15]
      f32x4 s[4];
#pragma unroll
      for (int jt = 0; jt < 4; ++jt)
        s[jt] = mfma16(kf[jt][hh], qf[it][hh], zero4);
      // p = exp2(s*ES + bias); row-sum over kv (regs + lq lanes)
      float rs = 0.f;
#pragma unroll
      for (int jt = 0; jt < 4; ++jt)
#pragma unroll
        for (int r = 0; r < 4; ++r) {
          s[jt][r] = __builtin_amdgcn_exp2f(s[jt][r] * EXPSCALE + bias4[jt][r]);
          rs += s[jt][r];
        }
      rs += __shfl_xor(rs, 16);
      rs += __shfl_xor(rs, 32);
      const float rinv = __builtin_amdgcn_rcpf(rs);

      // P -> wave-private scratch (P[q l15][kv]), packed b64
#pragma unroll
      for (int jt = 0; jt < 4; ++jt)
        *(uint2*)&pb[l15 * SB + jt * 16 + lq * 4] =
            pack4(s[jt][0], s[jt][1], s[jt][2], s[jt][3]);
      const bf16x8 ap0 = *(const bf16x8*)&pb[l15 * SB + lq * 8];
      const bf16x8 ap1 = *(const bf16x8*)&pb[l15 * SB + 32 + lq * 8];

      // oh^T = mfma(vT, P^T): D[feat ft*16+lq*4+r][q px it*16+l15]
      f32x4 o0 = mfma16(vf[0][0][hh], ap0, zero4);
      o0 = mfma16(vf[0][1][hh], ap1, o0);
      f32x4 o1 = mfma16(vf[1][0][hh], ap0, zero4);
      o1 = mfma16(vf[1][1][hh], ap1, o1);

      // normalize + stage oh (px-major shared region), packed b64
      *(uint2*)&oh_lds[(it * 16 + l15) * XO + w * 64 + hh * 32 + lq * 4] =
          pack4(o0[0] * rinv, o0[1] * rinv, o0[2] * rinv, o0[3] * rinv);
      *(uint2*)&oh_lds[(it * 16 + l15) * XO + w * 64 + hh * 32 + 16 + lq * 4] =
          pack4(o1[0] * rinv, o1[1] * rinv, o1[2] * rinv, o1[3] * rinv);
    }
  }
  __syncthreads();   // bar3: oh complete

  // ---------- phase 4: out-proj, one K=256 GEMM (swapped) + epilogue ----------
  {
    f32x4 ACC[4][4];
#pragma unroll
    for (int rt = 0; rt < 4; ++rt)
#pragma unroll
      for (int ct = 0; ct < 4; ++ct) ACC[rt][ct] = zero4;
#pragma unroll
    for (int kk = 0; kk < 8; ++kk) {
      bf16x8 a[4], b[4];
#pragma unroll
      for (int rt = 0; rt < 4; ++rt)
        a[rt] = *(const bf16x8*)&oh_lds[(rt * 16 + l15) * XO + kk * 32 + lq * 8];
#pragma unroll
      for (int ct = 0; ct < 4; ++ct)
        b[ct] = *(const bf16x8*)&woutT[(((w * 4 + ct) * 8 + kk) * 4 + lq) * 128 + l15 * 8];
#pragma unroll
      for (int rt = 0; rt < 4; ++rt)
#pragma unroll
        for (int ct = 0; ct < 4; ++ct)
          ACC[rt][ct] = mfma16(b[ct], a[rt], ACC[rt][ct]);   // D[ofeat][px]
    }
    // epilogue: D rows = ofeat w*64+ct*16+lq*4+r, cols = px rt*16+l15
#pragma unroll
    for (int rt = 0; rt < 4; ++rt) {
      const int p = rt * 16 + l15;
      float* orow = out + img_base +
          (((size_t)(wy * 8 + (p >> 3)) * 128) + (wx * 8 + (p & 7))) * 256;
#pragma unroll
      for (int ct = 0; ct < 4; ++ct) {
        const int n0 = w * 64 + ct * 16 + lq * 4;
        const f32x4 bo4 = *(const f32x4*)&b_out[n0];
        f32x4 st;
#pragma unroll
        for (int r = 0; r < 4; ++r) st[r] = ACC[rt][ct][r] + bo4[r];
        *(f32x4*)(orow + n0) = st;
      }
    }
  }
}

extern "C" void kernel_launch(void* const* d_in, const int* in_sizes, int n_in,
                              void* d_out, int out_size, void* d_ws, size_t ws_size,
                              hipStream_t stream) {
  const float* x       = (const float*)d_in[0];
  const float* w_qkv   = (const float*)d_in[1];
  const float* pos_emb = (const float*)d_in[2];
  const float* w_out   = (const float*)d_in[3];
  const float* b_out   = (const float*)d_in[4];
  float* out = (float*)d_out;

  unsigned short* wqkvT = (unsigned short*)d_ws;
  unsigned short* woutT = wqkvT + 768 * 256;
  float* bias64 = (float*)(woutT + 256 * 256);

  prep_kernel<<<96, 256, 0, stream>>>(w_qkv, w_out, pos_emb, wqkvT, woutT, bias64);
  winattn_kernel<<<2048, 256, 0, stream>>>(x, wqkvT, woutT, bias64, b_out, out);
}